// Round 18
// baseline (781.610 us; speedup 1.0000x reference)
//
#include <hip/hip_runtime.h>

typedef _Float16 f16;
typedef __attribute__((ext_vector_type(2))) _Float16 f16x2;
typedef __attribute__((ext_vector_type(8))) _Float16 f16x8;
typedef __attribute__((ext_vector_type(4))) float f32x4;

#define MFMA16(a,b,c) __builtin_amdgcn_mfma_f32_16x16x32_f16(a,b,c,0,0,0)

constexpr int NSEQ = 64;    // 2*8*4
constexpr int P    = 256;   // tokens per sequence
constexpr int DIMF = 768;
constexpr int NH   = 12;
constexpr int DH   = 64;
constexpr int M    = NSEQ * P;        // 16384
constexpr size_t XSZ = (size_t)M * DIMF;
constexpr size_t WSZ = (size_t)DIMF * DIMF;

__device__ __forceinline__ f16x8 cvt8(const float* p) {
    const float4 u = *(const float4*)p;
    const float4 w = *(const float4*)(p + 4);
    f16x2 a = __builtin_bit_cast(f16x2, __builtin_amdgcn_cvt_pkrtz(u.x, u.y));
    f16x2 b = __builtin_bit_cast(f16x2, __builtin_amdgcn_cvt_pkrtz(u.z, u.w));
    f16x2 c = __builtin_bit_cast(f16x2, __builtin_amdgcn_cvt_pkrtz(w.x, w.y));
    f16x2 d = __builtin_bit_cast(f16x2, __builtin_amdgcn_cvt_pkrtz(w.z, w.w));
    f16x8 r;
    r[0]=a[0]; r[1]=a[1]; r[2]=b[0]; r[3]=b[1];
    r[4]=c[0]; r[5]=c[1]; r[6]=d[0]; r[7]=d[1];
    return r;
}

__device__ __forceinline__ void gload16(const void* g, void* l) {
    __builtin_amdgcn_global_load_lds(
        (const __attribute__((address_space(1))) void*)g,
        (__attribute__((address_space(3))) void*)l, 16, 0, 0);
}

// ---- fp32 -> fp16 convert ----
__global__ __launch_bounds__(256) void conv_kernel(
    const float* __restrict__ x,
    const float* __restrict__ Wq, const float* __restrict__ Wk,
    const float* __restrict__ Wv,
    f16* __restrict__ xh, f16* __restrict__ wh)
{
    const size_t i8 = ((size_t)blockIdx.x * 256 + threadIdx.x) * 8;
    if (i8 < XSZ) {
        *(f16x8*)(xh + i8) = cvt8(x + i8);
    } else {
        const size_t j = i8 - XSZ;
        const int mtx = (int)(j / WSZ);
        const size_t r = j - (size_t)mtx * WSZ;
        const float* src = (mtx == 0 ? Wq : mtx == 1 ? Wk : Wv) + r;
        *(f16x8*)(wh + j) = cvt8(src);
    }
}

// ---- projection GEMM: 128x192 tile, BK=32, LDS 40KB -> 4 blocks/CU
// (32 waves/CU = HW max; TLP fills barrier stalls). Grid 1536.
// Staging split by wave group: waves 0-3 stage A (2 x 1KB units/step),
// waves 4-7 stage B (3 units/step); per-group counted vmcnt(2)/vmcnt(3)
// (per-wave FIFO: entry = own units of T; stage own units of T+1; wait
// retires exactly T's; barrier publishes block-wide).
// Unit = 16 rows x 4 chunks: lane l -> row u*16+(l>>2), src chunk
// (l&3)^((l>>3)&3) (64B-row swizzle c^=(row>>1)&3, r9-verified).
// LDS: A dbuf 2x8KB @0; B dbuf 2x12KB @16384. Total 40960.
__global__ __launch_bounds__(512, 8) void proj_gemm(
    const f16* __restrict__ xh, const f16* __restrict__ wh,
    const float* __restrict__ bq, const float* __restrict__ bk,
    const float* __restrict__ bv,
    f16* __restrict__ qout, f16* __restrict__ kout, f16* __restrict__ vt)
{
    __shared__ __align__(16) char smem[40960];
    const int wg = (blockIdx.x & 7) * 192 + (blockIdx.x >> 3);   // bijective (1536 = 8*192)
    const int nt = wg % 12;
    const int mt = wg / 12;           // 0..127
    const int m0 = mt * 128, n0 = nt * 192;

    const int tid  = threadIdx.x;
    const int lane = tid & 63;
    const int wave = tid >> 6;
    const int lr   = lane & 15;
    const int lg   = lane >> 4;
    const int wm   = wave >> 2;       // 0..1 : 64-row strip
    const int wn   = wave & 3;        // 0..3 : 48-col strip (3 frags)

    // staging source base (row = lane>>2 within unit; chunk pre-swizzled)
    const int schunk = ((lane & 3) ^ ((lane >> 3) & 3)) * 8;
    const f16* srcA0 = xh + (size_t)(m0 + (lane >> 2)) * DIMF + schunk;
    const f16* srcB0 = wh + (size_t)(n0 + (lane >> 2)) * DIMF + schunk;

    // fragment read bases (64B rows; swz = lg ^ ((row>>1)&3), row&15==lr)
    const int swz0 = (lg ^ ((lr >> 1) & 3)) * 16;
    const char* rA = smem + (wm * 64 + lr) * 64 + swz0;
    const char* rB = smem + 16384 + (wn * 48 + lr) * 64 + swz0;

    f32x4 acc[4][3];
    #pragma unroll
    for (int m = 0; m < 4; ++m)
        #pragma unroll
        for (int n = 0; n < 3; ++n) acc[m][n] = (f32x4){0.f,0.f,0.f,0.f};

    f16x8 a[4], bf[3];

    // stage K-step T into buf B: A-waves 2 units, B-waves 3 units
    #define STAGE(T, B) do {                                                  \
        if (wave < 4) {                                                       \
            _Pragma("unroll") for (int g = 0; g < 2; ++g) {                   \
                const int u = wave * 2 + g;                                   \
                gload16(srcA0 + (size_t)(u * 16) * DIMF + (T) * 32,           \
                        smem + (B) * 8192 + u * 1024 + lane * 16);            \
            }                                                                 \
        } else {                                                              \
            _Pragma("unroll") for (int g = 0; g < 3; ++g) {                   \
                const int u = (wave - 4) * 3 + g;                             \
                gload16(srcB0 + (size_t)(u * 16) * DIMF + (T) * 32,           \
                        smem + 16384 + (B) * 12288 + u * 1024 + lane * 16);   \
            }                                                                 \
        }                                                                     \
    } while (0)

    #define RD_A(B) do { _Pragma("unroll")                                    \
        for (int m = 0; m < 4; ++m)                                           \
            a[m] = *(const f16x8*)(rA + (B) * 8192 + m * 1024); } while (0)
    #define RD_BALL(B) do { _Pragma("unroll")                                 \
        for (int n = 0; n < 3; ++n)                                           \
            bf[n] = *(const f16x8*)(rB + (B) * 12288 + n * 1024); } while (0)

    #define CLUSTER() do {                                                    \
        __builtin_amdgcn_s_setprio(1);                                        \
        _Pragma("unroll") for (int m = 0; m < 4; ++m)                         \
        _Pragma("unroll") for (int n = 0; n < 3; ++n)                         \
            acc[m][n] = MFMA16(a[m], bf[n], acc[m][n]);                       \
        __builtin_amdgcn_s_setprio(0); } while (0)

    #define BAR  __builtin_amdgcn_s_barrier()
    #define LGKM asm volatile("s_waitcnt lgkmcnt(0)" ::: "memory")
    #define SCHB __builtin_amdgcn_sched_barrier(0)

    // one K-step (BK=32): 2 barriers, 1 counted wait, 7 ds_reads, 12 MFMA
    #define TILE(T, B, ST) do {                                               \
        BAR;   /* close step T-1: all waves done reading buf B^1 */           \
        if (ST) { STAGE((T)+1, (B)^1); SCHB;                                  \
                  if (wave < 4) { asm volatile("s_waitcnt vmcnt(2)" ::: "memory"); } \
                  else          { asm volatile("s_waitcnt vmcnt(3)" ::: "memory"); } } \
        else    { asm volatile("s_waitcnt vmcnt(0)" ::: "memory"); }          \
        BAR;   /* publish step T */                                           \
        SCHB;                                                                 \
        RD_A(B); RD_BALL(B);                                                  \
        LGKM; SCHB;                                                           \
        CLUSTER();                                                            \
    } while (0)

    // prologue: stage step 0 into buf0
    STAGE(0, 0);

    for (int it = 0; it < 12; ++it) {        // K = 768 = 24 x BK(32)
        TILE(2*it,     0, true);
        TILE(2*it + 1, 1, (it < 11));
    }

    __syncthreads();

    // ---- epilogue: 2 column-passes (96 cols each) via LDS bounce ----
    const int mat = nt >> 2;              // 0=q 1=k 2=v
    const int c0  = (nt & 3) * 192;
    const int h0  = (nt & 3) * 3;
    const int seq = mt >> 1;
    const int p0  = (mt & 1) * 128;
    const float* __restrict__ bias = mat == 0 ? bq : mat == 1 ? bk : bv;
    float bb[3];
    #pragma unroll
    for (int n = 0; n < 3; ++n) bb[n] = bias[c0 + wn*48 + n*16 + lr];

    f16 (*ep)[104] = (f16 (*)[104])smem;   // 128*104*2 = 26624 <= 40960
    #pragma unroll
    for (int cp = 0; cp < 2; ++cp) {
        if ((wn >> 1) == cp) {
            const int wn2 = wn & 1;       // 0..1 strip within this pass
            #pragma unroll
            for (int m = 0; m < 4; ++m)
                #pragma unroll
                for (int n = 0; n < 3; ++n)
                    #pragma unroll
                    for (int i = 0; i < 4; ++i)
                        ep[wm*64 + m*16 + lg*4 + i][wn2*48 + n*16 + lr] =
                            (f16)(acc[m][n][i] + bb[n]);
        }
        __syncthreads();
        if (mat < 2) {
            f16* __restrict__ dst = mat ? kout : qout;
            const int r = tid >> 2;           // 0..127
            #pragma unroll
            for (int s = 0; s < 3; ++s) {
                const int ch   = s*4 + (tid & 3);     // 0..11 (16B chunks of 96)
                const int colg = cp*96 + ch*8;        // 0..191
                const int h    = h0 + (colg >> 6);
                const int d0   = colg & 63;
                *(f16x8*)(dst + ((size_t)(seq*NH + h)*P + p0 + r)*DH + d0) =
                    *(const f16x8*)&ep[r][ch*8];
            }
        } else {
            if (tid < 192) {
                const int cl = tid >> 1, rg = tid & 1;    // col 0..95, 64-row half
                const int colg = cp*96 + cl;
                const int h = h0 + (colg >> 6), d = colg & 63;
                f16* drow = vt + ((size_t)(seq*NH + h)*DH + d)*P + p0 + rg*64;
                #pragma unroll
                for (int u = 0; u < 8; ++u) {
                    f16x8 vv;
                    #pragma unroll
                    for (int uu = 0; uu < 8; ++uu)
                        vv[uu] = ep[rg*64 + u*8 + uu][cl];
                    *(f16x8*)(drow + u*8) = vv;
                }
            }
        }
        __syncthreads();
    }
    #undef STAGE
    #undef RD_A
    #undef RD_BALL
    #undef CLUSTER
    #undef BAR
    #undef LGKM
    #undef SCHB
    #undef TILE
}

// ---- attention (round-15 passing kernel, unchanged) ----
__global__ __launch_bounds__(512) void attn_kernel(
    const f16* __restrict__ q, const f16* __restrict__ k,
    const f16* __restrict__ vt, float* __restrict__ out)
{
    __shared__ __align__(16) char kl[32768];
    __shared__ __align__(16) char vl[32768];
    __shared__ __align__(16) char pl[8][2048];

    const int n = blockIdx.x;                    // 1536 = 8 * 192
    const int b = (n & 7) * 192 + (n >> 3);
    const int half = b & 1;
    const int head = (b >> 1) % NH;
    const int seq  = b / (2 * NH);

    const int tid  = threadIdx.x;
    const int lane = tid & 63;
    const int wave = tid >> 6;
    const int lr   = lane & 15;
    const int lg   = lane >> 4;

    const f16* qh = q  + (size_t)(seq*NH + head)*P*DH;
    const f16* kh = k  + (size_t)(seq*NH + head)*P*DH;
    const f16* vh = vt + (size_t)(seq*NH + head)*DH*P;

    {
        const int r0 = tid >> 3, ck = tid & 7;
        const int d0 = tid >> 5, cv = tid & 31;
        #pragma unroll
        for (int it = 0; it < 4; ++it) {
            const int row = it * 64 + r0;
            gload16(kh + row * 64 + ((ck ^ (row & 7)) * 8), kl + it * 8192 + tid * 16);
            const int d = it * 16 + d0;
            gload16(vh + d * 256 + (((cv & 24) | ((cv ^ d) & 7)) * 8), vl + it * 8192 + tid * 16);
        }
    }

    const int qr0 = half * 128 + wave * 16;
    const f16x8 aq0 = *(const f16x8*)(qh + (qr0 + lr) * DH + lg * 8);
    const f16x8 aq1 = *(const f16x8*)(qh + (qr0 + lr) * DH + 32 + lg * 8);

    __syncthreads();

    f32x4 s[16];
    #pragma unroll
    for (int t = 0; t < 16; ++t) s[t] = (f32x4){0.f,0.f,0.f,0.f};
    __builtin_amdgcn_s_setprio(1);
    #pragma unroll
    for (int t = 0; t < 16; ++t) {
        const int row = t * 16 + lr;
        const f16x8 b0 = *(const f16x8*)(kl + row * 128 + ((lg ^ (row & 7)) * 16));
        const f16x8 b1 = *(const f16x8*)(kl + row * 128 + (((lg + 4) ^ (row & 7)) * 16));
        s[t] = MFMA16(aq0, b0, s[t]);
        s[t] = MFMA16(aq1, b1, s[t]);
    }
    __builtin_amdgcn_s_setprio(0);

    float mx[4] = {-1e30f, -1e30f, -1e30f, -1e30f};
    #pragma unroll
    for (int t = 0; t < 16; ++t)
        #pragma unroll
        for (int i = 0; i < 4; ++i) mx[i] = fmaxf(mx[i], s[t][i]);
    #pragma unroll
    for (int st = 1; st < 16; st <<= 1)
        #pragma unroll
        for (int i = 0; i < 4; ++i) mx[i] = fmaxf(mx[i], __shfl_xor(mx[i], st));

    const float SCL = 0.125f * 1.44269504088896f;
    float rs[4] = {0.f, 0.f, 0.f, 0.f};
    #pragma unroll
    for (int t = 0; t < 16; ++t)
        #pragma unroll
        for (int i = 0; i < 4; ++i) {
            const float e = exp2f((s[t][i] - mx[i]) * SCL);
            s[t][i] = e;
            rs[i] += e;
        }
    #pragma unroll
    for (int st = 1; st < 16; st <<= 1)
        #pragma unroll
        for (int i = 0; i < 4; ++i) rs[i] += __shfl_xor(rs[i], st);

    char* pw = pl[wave];
    f32x4 o[4];
    #pragma unroll
    for (int t = 0; t < 4; ++t) o[t] = (f32x4){0.f,0.f,0.f,0.f};

    #pragma unroll
    for (int qq = 0; qq < 4; ++qq) {
        #pragma unroll
        for (int tt = 0; tt < 4; ++tt) {
            const int t = qq * 4 + tt;
            #pragma unroll
            for (int i = 0; i < 4; ++i) {
                const int r = lg * 4 + i;
                const int klocal = tt * 16 + lr;
                *(f16*)(pw + r * 128 + ((klocal * 2) ^ ((r & 7) << 4))) = (f16)s[t][i];
            }
        }
        __builtin_amdgcn_s_setprio(1);
        #pragma unroll
        for (int kol = 0; kol < 2; ++kol) {
            const f16x8 ap = *(const f16x8*)(pw + lr * 128 + (((kol * 4 + lg) ^ (lr & 7)) * 16));
            #pragma unroll
            for (int dt = 0; dt < 4; ++dt) {
                const int row = dt * 16 + lr;
                const int ch  = qq * 8 + kol * 4 + lg;
                const f16x8 bv_ = *(const f16x8*)(vl + row * 512 + (((ch & 24) | ((ch ^ row) & 7)) * 16));
                o[dt] = MFMA16(ap, bv_, o[dt]);
            }
        }
        __builtin_amdgcn_s_setprio(0);
    }

    #pragma unroll
    for (int i = 0; i < 4; ++i) rs[i] = 1.f / rs[i];
    float* op = out + ((size_t)seq * P + qr0) * DIMF + head * DH;
    #pragma unroll
    for (int t = 0; t < 4; ++t)
        #pragma unroll
        for (int i = 0; i < 4; ++i)
            op[(lg * 4 + i) * DIMF + t * 16 + lr] = o[t][i] * rs[i];
}

extern "C" void kernel_launch(void* const* d_in, const int* in_sizes, int n_in,
                              void* d_out, int out_size, void* d_ws, size_t ws_size,
                              hipStream_t stream) {
    const float* x  = (const float*)d_in[0];
    const float* Wq = (const float*)d_in[1];
    const float* bq = (const float*)d_in[2];
    const float* Wk = (const float*)d_in[3];
    const float* bk = (const float*)d_in[4];
    const float* Wv = (const float*)d_in[5];
    const float* bv = (const float*)d_in[6];
    float* out = (float*)d_out;

    f16* xh = (f16*)d_out;          // fp16 staging lives in d_out (fully consumed
    f16* wh = xh + XSZ;             // by proj_gemm before attn overwrites d_out)

    const size_t QSZ = (size_t)M * DIMF;
    f16* q  = (f16*)d_ws;
    f16* k  = q + QSZ;
    f16* vt = k + QSZ;

    const int convThreads = (int)((XSZ + 3 * WSZ) / 8);
    conv_kernel<<<convThreads / 256, 256, 0, stream>>>(x, Wq, Wk, Wv, xh, wh);
    proj_gemm<<<dim3(1536), 512, 0, stream>>>(xh, wh, bq, bk, bv, q, k, vt);
    attn_kernel<<<dim3(NSEQ * NH * 2), 512, 0, stream>>>(q, k, vt, out);
}

// Round 19
// 123.451 us; speedup vs baseline: 6.3314x; 6.3314x over previous
//
#include <hip/hip_runtime.h>

typedef _Float16 f16;
typedef __attribute__((ext_vector_type(2))) _Float16 f16x2;
typedef __attribute__((ext_vector_type(8))) _Float16 f16x8;
typedef __attribute__((ext_vector_type(4))) float f32x4;

#define MFMA16(a,b,c) __builtin_amdgcn_mfma_f32_16x16x32_f16(a,b,c,0,0,0)

constexpr int NSEQ = 64;    // 2*8*4
constexpr int P    = 256;   // tokens per sequence
constexpr int DIMF = 768;
constexpr int NH   = 12;
constexpr int DH   = 64;
constexpr int M    = NSEQ * P;        // 16384
constexpr size_t XSZ = (size_t)M * DIMF;
constexpr size_t WSZ = (size_t)DIMF * DIMF;

__device__ __forceinline__ f16x8 cvt8(const float* p) {
    const float4 u = *(const float4*)p;
    const float4 w = *(const float4*)(p + 4);
    f16x2 a = __builtin_bit_cast(f16x2, __builtin_amdgcn_cvt_pkrtz(u.x, u.y));
    f16x2 b = __builtin_bit_cast(f16x2, __builtin_amdgcn_cvt_pkrtz(u.z, u.w));
    f16x2 c = __builtin_bit_cast(f16x2, __builtin_amdgcn_cvt_pkrtz(w.x, w.y));
    f16x2 d = __builtin_bit_cast(f16x2, __builtin_amdgcn_cvt_pkrtz(w.z, w.w));
    f16x8 r;
    r[0]=a[0]; r[1]=a[1]; r[2]=b[0]; r[3]=b[1];
    r[4]=c[0]; r[5]=c[1]; r[6]=d[0]; r[7]=d[1];
    return r;
}

__device__ __forceinline__ void gload16(const void* g, void* l) {
    __builtin_amdgcn_global_load_lds(
        (const __attribute__((address_space(1))) void*)g,
        (__attribute__((address_space(3))) void*)l, 16, 0, 0);
}

// ---- fp32 -> fp16 convert ----
__global__ __launch_bounds__(256) void conv_kernel(
    const float* __restrict__ x,
    const float* __restrict__ Wq, const float* __restrict__ Wk,
    const float* __restrict__ Wv,
    f16* __restrict__ xh, f16* __restrict__ wh)
{
    const size_t i8 = ((size_t)blockIdx.x * 256 + threadIdx.x) * 8;
    if (i8 < XSZ) {
        *(f16x8*)(xh + i8) = cvt8(x + i8);
    } else {
        const size_t j = i8 - XSZ;
        const int mtx = (int)(j / WSZ);
        const size_t r = j - (size_t)mtx * WSZ;
        const float* src = (mtx == 0 ? Wq : mtx == 1 ? Wk : Wv) + r;
        *(f16x8*)(wh + j) = cvt8(src);
    }
}

// ---- projection GEMM: 128x192 tile, BK=32, LDS 40KB. launch_bounds(512,4)
// (VGPR cap 128 -> NO spill; r18's (512,8) forced VGPR<=64-class budget and
// spilled acc to scratch: VGPR=32, 3.4GB scratch traffic, 779us).
// Occupancy = min(LDS 160/40=4, VGPR 512/ceil(used)/8) -> 3-4 blocks/CU.
// Staging split by wave group: waves 0-3 stage A (2 x 1KB units/step),
// waves 4-7 stage B (3 units/step); per-group counted vmcnt(2)/vmcnt(3).
// Unit = 16 rows x 4 chunks; 64B-row swizzle c^=(row>>1)&3 (r9-verified).
// LDS: A dbuf 2x8KB @0; B dbuf 2x12KB @16384. Total 40960.
__global__ __launch_bounds__(512, 4) void proj_gemm(
    const f16* __restrict__ xh, const f16* __restrict__ wh,
    const float* __restrict__ bq, const float* __restrict__ bk,
    const float* __restrict__ bv,
    f16* __restrict__ qout, f16* __restrict__ kout, f16* __restrict__ vt)
{
    __shared__ __align__(16) char smem[40960];
    const int wg = (blockIdx.x & 7) * 192 + (blockIdx.x >> 3);   // bijective (1536 = 8*192)
    const int nt = wg % 12;
    const int mt = wg / 12;           // 0..127
    const int m0 = mt * 128, n0 = nt * 192;

    const int tid  = threadIdx.x;
    const int lane = tid & 63;
    const int wave = tid >> 6;
    const int lr   = lane & 15;
    const int lg   = lane >> 4;
    const int wm   = wave >> 2;       // 0..1 : 64-row strip
    const int wn   = wave & 3;        // 0..3 : 48-col strip (3 frags)

    // staging source base (row = lane>>2 within unit; chunk pre-swizzled)
    const int schunk = ((lane & 3) ^ ((lane >> 3) & 3)) * 8;
    const f16* srcA0 = xh + (size_t)(m0 + (lane >> 2)) * DIMF + schunk;
    const f16* srcB0 = wh + (size_t)(n0 + (lane >> 2)) * DIMF + schunk;

    // fragment read bases (64B rows; swz = lg ^ ((row>>1)&3), row&15==lr)
    const int swz0 = (lg ^ ((lr >> 1) & 3)) * 16;
    const char* rA = smem + (wm * 64 + lr) * 64 + swz0;
    const char* rB = smem + 16384 + (wn * 48 + lr) * 64 + swz0;

    f32x4 acc[4][3];
    #pragma unroll
    for (int m = 0; m < 4; ++m)
        #pragma unroll
        for (int n = 0; n < 3; ++n) acc[m][n] = (f32x4){0.f,0.f,0.f,0.f};

    f16x8 a[4], bf[3];

    // stage K-step T into buf B: A-waves 2 units, B-waves 3 units
    #define STAGE(T, B) do {                                                  \
        if (wave < 4) {                                                       \
            _Pragma("unroll") for (int g = 0; g < 2; ++g) {                   \
                const int u = wave * 2 + g;                                   \
                gload16(srcA0 + (size_t)(u * 16) * DIMF + (T) * 32,           \
                        smem + (B) * 8192 + u * 1024 + lane * 16);            \
            }                                                                 \
        } else {                                                              \
            _Pragma("unroll") for (int g = 0; g < 3; ++g) {                   \
                const int u = (wave - 4) * 3 + g;                             \
                gload16(srcB0 + (size_t)(u * 16) * DIMF + (T) * 32,           \
                        smem + 16384 + (B) * 12288 + u * 1024 + lane * 16);   \
            }                                                                 \
        }                                                                     \
    } while (0)

    #define RD_A(B) do { _Pragma("unroll")                                    \
        for (int m = 0; m < 4; ++m)                                           \
            a[m] = *(const f16x8*)(rA + (B) * 8192 + m * 1024); } while (0)
    #define RD_BALL(B) do { _Pragma("unroll")                                 \
        for (int n = 0; n < 3; ++n)                                           \
            bf[n] = *(const f16x8*)(rB + (B) * 12288 + n * 1024); } while (0)

    #define CLUSTER() do {                                                    \
        __builtin_amdgcn_s_setprio(1);                                        \
        _Pragma("unroll") for (int m = 0; m < 4; ++m)                         \
        _Pragma("unroll") for (int n = 0; n < 3; ++n)                         \
            acc[m][n] = MFMA16(a[m], bf[n], acc[m][n]);                       \
        __builtin_amdgcn_s_setprio(0); } while (0)

    #define BAR  __builtin_amdgcn_s_barrier()
    #define LGKM asm volatile("s_waitcnt lgkmcnt(0)" ::: "memory")
    #define SCHB __builtin_amdgcn_sched_barrier(0)

    // one K-step (BK=32): 2 barriers, 1 counted wait, 7 ds_reads, 12 MFMA
    #define TILE(T, B, ST) do {                                               \
        BAR;   /* close step T-1: all waves done reading buf B^1 */           \
        if (ST) { STAGE((T)+1, (B)^1); SCHB;                                  \
                  if (wave < 4) { asm volatile("s_waitcnt vmcnt(2)" ::: "memory"); } \
                  else          { asm volatile("s_waitcnt vmcnt(3)" ::: "memory"); } } \
        else    { asm volatile("s_waitcnt vmcnt(0)" ::: "memory"); }          \
        BAR;   /* publish step T */                                           \
        SCHB;                                                                 \
        RD_A(B); RD_BALL(B);                                                  \
        LGKM; SCHB;                                                           \
        CLUSTER();                                                            \
    } while (0)

    // prologue: stage step 0 into buf0
    STAGE(0, 0);

    for (int it = 0; it < 12; ++it) {        // K = 768 = 24 x BK(32)
        TILE(2*it,     0, true);
        TILE(2*it + 1, 1, (it < 11));
    }

    __syncthreads();

    // ---- epilogue: 2 column-passes (96 cols each) via LDS bounce ----
    const int mat = nt >> 2;              // 0=q 1=k 2=v
    const int c0  = (nt & 3) * 192;
    const int h0  = (nt & 3) * 3;
    const int seq = mt >> 1;
    const int p0  = (mt & 1) * 128;
    const float* __restrict__ bias = mat == 0 ? bq : mat == 1 ? bk : bv;
    float bb[3];
    #pragma unroll
    for (int n = 0; n < 3; ++n) bb[n] = bias[c0 + wn*48 + n*16 + lr];

    f16 (*ep)[104] = (f16 (*)[104])smem;   // 128*104*2 = 26624 <= 40960
    #pragma unroll
    for (int cp = 0; cp < 2; ++cp) {
        if ((wn >> 1) == cp) {
            const int wn2 = wn & 1;       // 0..1 strip within this pass
            #pragma unroll
            for (int m = 0; m < 4; ++m)
                #pragma unroll
                for (int n = 0; n < 3; ++n)
                    #pragma unroll
                    for (int i = 0; i < 4; ++i)
                        ep[wm*64 + m*16 + lg*4 + i][wn2*48 + n*16 + lr] =
                            (f16)(acc[m][n][i] + bb[n]);
        }
        __syncthreads();
        if (mat < 2) {
            f16* __restrict__ dst = mat ? kout : qout;
            const int r = tid >> 2;           // 0..127
            #pragma unroll
            for (int s = 0; s < 3; ++s) {
                const int ch   = s*4 + (tid & 3);     // 0..11 (16B chunks of 96)
                const int colg = cp*96 + ch*8;        // 0..191
                const int h    = h0 + (colg >> 6);
                const int d0   = colg & 63;
                *(f16x8*)(dst + ((size_t)(seq*NH + h)*P + p0 + r)*DH + d0) =
                    *(const f16x8*)&ep[r][ch*8];
            }
        } else {
            if (tid < 192) {
                const int cl = tid >> 1, rg = tid & 1;    // col 0..95, 64-row half
                const int colg = cp*96 + cl;
                const int h = h0 + (colg >> 6), d = colg & 63;
                f16* drow = vt + ((size_t)(seq*NH + h)*DH + d)*P + p0 + rg*64;
                #pragma unroll
                for (int u = 0; u < 8; ++u) {
                    f16x8 vv;
                    #pragma unroll
                    for (int uu = 0; uu < 8; ++uu)
                        vv[uu] = ep[rg*64 + u*8 + uu][cl];
                    *(f16x8*)(drow + u*8) = vv;
                }
            }
        }
        __syncthreads();
    }
    #undef STAGE
    #undef RD_A
    #undef RD_BALL
    #undef CLUSTER
    #undef BAR
    #undef LGKM
    #undef SCHB
    #undef TILE
}

// ---- attention (round-15 passing kernel, unchanged) ----
__global__ __launch_bounds__(512) void attn_kernel(
    const f16* __restrict__ q, const f16* __restrict__ k,
    const f16* __restrict__ vt, float* __restrict__ out)
{
    __shared__ __align__(16) char kl[32768];
    __shared__ __align__(16) char vl[32768];
    __shared__ __align__(16) char pl[8][2048];

    const int n = blockIdx.x;                    // 1536 = 8 * 192
    const int b = (n & 7) * 192 + (n >> 3);
    const int half = b & 1;
    const int head = (b >> 1) % NH;
    const int seq  = b / (2 * NH);

    const int tid  = threadIdx.x;
    const int lane = tid & 63;
    const int wave = tid >> 6;
    const int lr   = lane & 15;
    const int lg   = lane >> 4;

    const f16* qh = q  + (size_t)(seq*NH + head)*P*DH;
    const f16* kh = k  + (size_t)(seq*NH + head)*P*DH;
    const f16* vh = vt + (size_t)(seq*NH + head)*DH*P;

    {
        const int r0 = tid >> 3, ck = tid & 7;
        const int d0 = tid >> 5, cv = tid & 31;
        #pragma unroll
        for (int it = 0; it < 4; ++it) {
            const int row = it * 64 + r0;
            gload16(kh + row * 64 + ((ck ^ (row & 7)) * 8), kl + it * 8192 + tid * 16);
            const int d = it * 16 + d0;
            gload16(vh + d * 256 + (((cv & 24) | ((cv ^ d) & 7)) * 8), vl + it * 8192 + tid * 16);
        }
    }

    const int qr0 = half * 128 + wave * 16;
    const f16x8 aq0 = *(const f16x8*)(qh + (qr0 + lr) * DH + lg * 8);
    const f16x8 aq1 = *(const f16x8*)(qh + (qr0 + lr) * DH + 32 + lg * 8);

    __syncthreads();

    f32x4 s[16];
    #pragma unroll
    for (int t = 0; t < 16; ++t) s[t] = (f32x4){0.f,0.f,0.f,0.f};
    __builtin_amdgcn_s_setprio(1);
    #pragma unroll
    for (int t = 0; t < 16; ++t) {
        const int row = t * 16 + lr;
        const f16x8 b0 = *(const f16x8*)(kl + row * 128 + ((lg ^ (row & 7)) * 16));
        const f16x8 b1 = *(const f16x8*)(kl + row * 128 + (((lg + 4) ^ (row & 7)) * 16));
        s[t] = MFMA16(aq0, b0, s[t]);
        s[t] = MFMA16(aq1, b1, s[t]);
    }
    __builtin_amdgcn_s_setprio(0);

    float mx[4] = {-1e30f, -1e30f, -1e30f, -1e30f};
    #pragma unroll
    for (int t = 0; t < 16; ++t)
        #pragma unroll
        for (int i = 0; i < 4; ++i) mx[i] = fmaxf(mx[i], s[t][i]);
    #pragma unroll
    for (int st = 1; st < 16; st <<= 1)
        #pragma unroll
        for (int i = 0; i < 4; ++i) mx[i] = fmaxf(mx[i], __shfl_xor(mx[i], st));

    const float SCL = 0.125f * 1.44269504088896f;
    float rs[4] = {0.f, 0.f, 0.f, 0.f};
    #pragma unroll
    for (int t = 0; t < 16; ++t)
        #pragma unroll
        for (int i = 0; i < 4; ++i) {
            const float e = exp2f((s[t][i] - mx[i]) * SCL);
            s[t][i] = e;
            rs[i] += e;
        }
    #pragma unroll
    for (int st = 1; st < 16; st <<= 1)
        #pragma unroll
        for (int i = 0; i < 4; ++i) rs[i] += __shfl_xor(rs[i], st);

    char* pw = pl[wave];
    f32x4 o[4];
    #pragma unroll
    for (int t = 0; t < 4; ++t) o[t] = (f32x4){0.f,0.f,0.f,0.f};

    #pragma unroll
    for (int qq = 0; qq < 4; ++qq) {
        #pragma unroll
        for (int tt = 0; tt < 4; ++tt) {
            const int t = qq * 4 + tt;
            #pragma unroll
            for (int i = 0; i < 4; ++i) {
                const int r = lg * 4 + i;
                const int klocal = tt * 16 + lr;
                *(f16*)(pw + r * 128 + ((klocal * 2) ^ ((r & 7) << 4))) = (f16)s[t][i];
            }
        }
        __builtin_amdgcn_s_setprio(1);
        #pragma unroll
        for (int kol = 0; kol < 2; ++kol) {
            const f16x8 ap = *(const f16x8*)(pw + lr * 128 + (((kol * 4 + lg) ^ (lr & 7)) * 16));
            #pragma unroll
            for (int dt = 0; dt < 4; ++dt) {
                const int row = dt * 16 + lr;
                const int ch  = qq * 8 + kol * 4 + lg;
                const f16x8 bv_ = *(const f16x8*)(vl + row * 512 + (((ch & 24) | ((ch ^ row) & 7)) * 16));
                o[dt] = MFMA16(ap, bv_, o[dt]);
            }
        }
        __builtin_amdgcn_s_setprio(0);
    }

    #pragma unroll
    for (int i = 0; i < 4; ++i) rs[i] = 1.f / rs[i];
    float* op = out + ((size_t)seq * P + qr0) * DIMF + head * DH;
    #pragma unroll
    for (int t = 0; t < 4; ++t)
        #pragma unroll
        for (int i = 0; i < 4; ++i)
            op[(lg * 4 + i) * DIMF + t * 16 + lr] = o[t][i] * rs[i];
}

extern "C" void kernel_launch(void* const* d_in, const int* in_sizes, int n_in,
                              void* d_out, int out_size, void* d_ws, size_t ws_size,
                              hipStream_t stream) {
    const float* x  = (const float*)d_in[0];
    const float* Wq = (const float*)d_in[1];
    const float* bq = (const float*)d_in[2];
    const float* Wk = (const float*)d_in[3];
    const float* bk = (const float*)d_in[4];
    const float* Wv = (const float*)d_in[5];
    const float* bv = (const float*)d_in[6];
    float* out = (float*)d_out;

    f16* xh = (f16*)d_out;          // fp16 staging lives in d_out (fully consumed
    f16* wh = xh + XSZ;             // by proj_gemm before attn overwrites d_out)

    const size_t QSZ = (size_t)M * DIMF;
    f16* q  = (f16*)d_ws;
    f16* k  = q + QSZ;
    f16* vt = k + QSZ;

    const int convThreads = (int)((XSZ + 3 * WSZ) / 8);
    conv_kernel<<<convThreads / 256, 256, 0, stream>>>(x, Wq, Wk, Wv, xh, wh);
    proj_gemm<<<dim3(1536), 512, 0, stream>>>(xh, wh, bq, bk, bv, q, k, vt);
    attn_kernel<<<dim3(NSEQ * NH * 2), 512, 0, stream>>>(q, k, vt, out);
}

// Round 20
// 112.649 us; speedup vs baseline: 6.9384x; 1.0959x over previous
//
#include <hip/hip_runtime.h>

typedef _Float16 f16;
typedef __attribute__((ext_vector_type(2))) _Float16 f16x2;
typedef __attribute__((ext_vector_type(8))) _Float16 f16x8;
typedef __attribute__((ext_vector_type(4))) float f32x4;

#define MFMA16(a,b,c) __builtin_amdgcn_mfma_f32_16x16x32_f16(a,b,c,0,0,0)

constexpr int NSEQ = 64;    // 2*8*4
constexpr int P    = 256;   // tokens per sequence
constexpr int DIMF = 768;
constexpr int NH   = 12;
constexpr int DH   = 64;
constexpr int M    = NSEQ * P;        // 16384
constexpr size_t XSZ = (size_t)M * DIMF;
constexpr size_t WSZ = (size_t)DIMF * DIMF;

__device__ __forceinline__ f16x8 cvt8(const float* p) {
    const float4 u = *(const float4*)p;
    const float4 w = *(const float4*)(p + 4);
    f16x2 a = __builtin_bit_cast(f16x2, __builtin_amdgcn_cvt_pkrtz(u.x, u.y));
    f16x2 b = __builtin_bit_cast(f16x2, __builtin_amdgcn_cvt_pkrtz(u.z, u.w));
    f16x2 c = __builtin_bit_cast(f16x2, __builtin_amdgcn_cvt_pkrtz(w.x, w.y));
    f16x2 d = __builtin_bit_cast(f16x2, __builtin_amdgcn_cvt_pkrtz(w.z, w.w));
    f16x8 r;
    r[0]=a[0]; r[1]=a[1]; r[2]=b[0]; r[3]=b[1];
    r[4]=c[0]; r[5]=c[1]; r[6]=d[0]; r[7]=d[1];
    return r;
}

__device__ __forceinline__ void gload16(const void* g, void* l) {
    __builtin_amdgcn_global_load_lds(
        (const __attribute__((address_space(1))) void*)g,
        (__attribute__((address_space(3))) void*)l, 16, 0, 0);
}

// ---- fp32 -> fp16 convert ----
__global__ __launch_bounds__(256) void conv_kernel(
    const float* __restrict__ x,
    const float* __restrict__ Wq, const float* __restrict__ Wk,
    const float* __restrict__ Wv,
    f16* __restrict__ xh, f16* __restrict__ wh)
{
    const size_t i8 = ((size_t)blockIdx.x * 256 + threadIdx.x) * 8;
    if (i8 < XSZ) {
        *(f16x8*)(xh + i8) = cvt8(x + i8);
    } else {
        const size_t j = i8 - XSZ;
        const int mtx = (int)(j / WSZ);
        const size_t r = j - (size_t)mtx * WSZ;
        const float* src = (mtx == 0 ? Wq : mtx == 1 ? Wk : Wv) + r;
        *(f16x8*)(wh + j) = cvt8(src);
    }
}

// ---- projection GEMM: 128x192 tile, BK=64, LDS 80KB -> 2 blocks/CU (TLP
// fills barrier stalls). Grid 1536 = 3 FULL rounds of 512 resident blocks.
// Per K-tile: {BAR; stage 5 units of T+1; vmcnt(5) retiring exactly tile T
// (FIFO: 5 old + 5 new); BAR; 14 ds_reads; 24 MFMA}. Units = 64 rows,
// 1 gload/thread, order Aa,Ab,B0,B1,B2 (prologue & steady identical).
// LDS: A dbuf 2x16KB @0; B dbuf 2x24KB @32768. Chunk-swz c^=row&7 (r16's).
// MEASURED BEST: proj 68-71us, total 112.7us (round 17). Occupancy sweep:
// 1 blk/CU (256^2)=81us, 2 blk/CU (this)=69us, 4 blk/CU (BK=32)=87us.
__global__ __launch_bounds__(512, 4) void proj_gemm(
    const f16* __restrict__ xh, const f16* __restrict__ wh,
    const float* __restrict__ bq, const float* __restrict__ bk,
    const float* __restrict__ bv,
    f16* __restrict__ qout, f16* __restrict__ kout, f16* __restrict__ vt)
{
    __shared__ __align__(16) char smem[81920];
    const int wg = (blockIdx.x & 7) * 192 + (blockIdx.x >> 3);   // bijective (1536 = 8*192)
    const int nt = wg % 12;
    const int mt = wg / 12;           // 0..127
    const int m0 = mt * 128, n0 = nt * 192;

    const int tid  = threadIdx.x;
    const int lane = tid & 63;
    const int wave = tid >> 6;
    const int lr   = lane & 15;
    const int lg   = lane >> 4;
    const int wm   = wave >> 2;       // 0..1 : 64-row strip
    const int wn   = wave & 3;        // 0..3 : 48-col strip (3 frags)

    // staging source (chunk-swizzled: LDS chunk c holds global chunk c^(row&7))
    const f16* srcA = xh + (size_t)(m0 + (tid >> 3)) * DIMF + ((tid & 7) ^ ((tid >> 3) & 7)) * 8;
    const f16* srcB = wh + (size_t)(n0 + (tid >> 3)) * DIMF + ((tid & 7) ^ ((tid >> 3) & 7)) * 8;
    char* dA = smem + tid * 16;
    char* dB = smem + 32768 + tid * 16;

    // fragment read bases (row&7 == lr&7 for all fragment rows)
    const int swz0 = (lg ^ (lr & 7)) * 16;
    const char* rA = smem + (wm * 64 + lr) * 128;
    const char* rB = smem + 32768 + (wn * 48 + lr) * 128;

    f32x4 acc[4][3];
    #pragma unroll
    for (int m = 0; m < 4; ++m)
        #pragma unroll
        for (int n = 0; n < 3; ++n) acc[m][n] = (f32x4){0.f,0.f,0.f,0.f};

    f16x8 a[4][2], bf[3][2];

    // A tile (128 rows = 2 units Aa,Ab) of K-tile T into buf B
    #define STA(T, B) do {                                                        \
        gload16(srcA + (T)*64,                       dA + (B)*16384);             \
        gload16(srcA + (size_t)(64*DIMF) + (T)*64,   dA + (B)*16384 + 8192); } while (0)
    // B unit U (64 rows) of K-tile T into buf B
    #define STB(U, T, B)                                                          \
        gload16(srcB + (size_t)((U)*64) * DIMF + (T)*64, dB + (B)*24576 + (U)*8192)

    #define RD_A(B) do { _Pragma("unroll")                                        \
        for (int m = 0; m < 4; ++m) {                                             \
            a[m][0] = *(const f16x8*)(rA + (B)*16384 + m*2048 + swz0);            \
            a[m][1] = *(const f16x8*)(rA + (B)*16384 + m*2048 + (swz0^64)); } } while (0)
    #define RD_BALL(B) do { _Pragma("unroll")                                     \
        for (int n = 0; n < 3; ++n) {                                             \
            bf[n][0] = *(const f16x8*)(rB + (B)*24576 + n*2048 + swz0);           \
            bf[n][1] = *(const f16x8*)(rB + (B)*24576 + n*2048 + (swz0^64)); } } while (0)

    #define CLUSTER() do {                                                        \
        __builtin_amdgcn_s_setprio(1);                                            \
        _Pragma("unroll") for (int m = 0; m < 4; ++m)                             \
        _Pragma("unroll") for (int n = 0; n < 3; ++n) {                           \
            acc[m][n] = MFMA16(a[m][0], bf[n][0], acc[m][n]);                     \
            acc[m][n] = MFMA16(a[m][1], bf[n][1], acc[m][n]); }                   \
        __builtin_amdgcn_s_setprio(0); } while (0)

    #define BAR  __builtin_amdgcn_s_barrier()
    #define LGKM asm volatile("s_waitcnt lgkmcnt(0)" ::: "memory")
    #define SCHB __builtin_amdgcn_sched_barrier(0)

    // one K-tile: 2 barriers, 1 counted vmcnt, 14 ds_reads, 24 MFMA.
    // Ledger: entry queue = 5 units of tile T (order Aa,Ab,B0,B1,B2).
    // Stage 5 of T+1 -> queue 10; vmcnt(5) retires exactly tile T. BAR
    // publishes tile T block-wide (each wave's own 5 retired + rendezvous).
    #define TILE(T, B, ST) do {                                                   \
        BAR;   /* close tile T-1: all waves done reading buf B^1 */               \
        if (ST) { STA((T)+1, (B)^1);                                              \
                  STB(0, (T)+1, (B)^1); STB(1, (T)+1, (B)^1); STB(2, (T)+1, (B)^1); \
                  SCHB; asm volatile("s_waitcnt vmcnt(5)" ::: "memory"); }        \
        else    { asm volatile("s_waitcnt vmcnt(0)" ::: "memory"); }              \
        BAR;   /* publish tile T */                                               \
        SCHB;                                                                     \
        RD_A(B); RD_BALL(B);                                                      \
        LGKM; SCHB;                                                               \
        CLUSTER();                                                                \
    } while (0)

    // prologue: stage tile 0 into buf0 (5 gloads, need order Aa,Ab,B0,B1,B2)
    STA(0, 0); STB(0, 0, 0); STB(1, 0, 0); STB(2, 0, 0);

    for (int it = 0; it < 6; ++it) {
        TILE(2*it,     0, true);
        TILE(2*it + 1, 1, (it < 5));
    }

    __syncthreads();

    // ---- epilogue: single-pass LDS bounce (128 rows x 192 cols) ----
    const int mat = nt >> 2;              // 0=q 1=k 2=v   (nt: 0-3 q, 4-7 k, 8-11 v)
    const int c0  = (nt & 3) * 192;       // col offset within matrix
    const int h0  = (nt & 3) * 3;         // first of 3 heads in this tile
    const int seq = mt >> 1;
    const int p0  = (mt & 1) * 128;
    const float* __restrict__ bias = mat == 0 ? bq : mat == 1 ? bk : bv;
    float bb[3];
    #pragma unroll
    for (int n = 0; n < 3; ++n) bb[n] = bias[c0 + wn*48 + n*16 + lr];

    f16 (*ep)[200] = (f16 (*)[200])smem;   // 128*200*2 = 51200 B <= 80KB
    #pragma unroll
    for (int m = 0; m < 4; ++m)
        #pragma unroll
        for (int n = 0; n < 3; ++n)
            #pragma unroll
            for (int i = 0; i < 4; ++i)
                ep[wm*64 + m*16 + lg*4 + i][wn*48 + n*16 + lr] =
                    (f16)(acc[m][n][i] + bb[n]);
    __syncthreads();
    if (mat < 2) {
        f16* __restrict__ dst = mat ? kout : qout;
        const int r = tid >> 2;           // 0..127
        #pragma unroll
        for (int s = 0; s < 6; ++s) {
            const int ch = s*4 + (tid & 3);       // 0..23 (16B chunks of 192 cols)
            const int h  = h0 + (ch >> 3);
            const int d0 = (ch & 7) * 8;
            *(f16x8*)(dst + ((size_t)(seq*NH + h)*P + p0 + r)*DH + d0) =
                *(const f16x8*)&ep[r][ch*8];
        }
    } else {
        if (tid < 384) {
            const int col = tid >> 1, rg = tid & 1;   // col 0..191
            const int h = h0 + (col >> 6), d = col & 63;
            f16* drow = vt + ((size_t)(seq*NH + h)*DH + d)*P + p0 + rg*64;
            #pragma unroll
            for (int u = 0; u < 8; ++u) {
                f16x8 vv;
                #pragma unroll
                for (int uu = 0; uu < 8; ++uu)
                    vv[uu] = ep[rg*64 + u*8 + uu][col];
                *(f16x8*)(drow + u*8) = vv;
            }
        }
    }
    #undef STA
    #undef STB
    #undef RD_A
    #undef RD_BALL
    #undef CLUSTER
    #undef BAR
    #undef LGKM
    #undef SCHB
    #undef TILE
}

// ---- attention (round-15 passing kernel, unchanged) ----
__global__ __launch_bounds__(512) void attn_kernel(
    const f16* __restrict__ q, const f16* __restrict__ k,
    const f16* __restrict__ vt, float* __restrict__ out)
{
    __shared__ __align__(16) char kl[32768];
    __shared__ __align__(16) char vl[32768];
    __shared__ __align__(16) char pl[8][2048];

    const int n = blockIdx.x;                    // 1536 = 8 * 192
    const int b = (n & 7) * 192 + (n >> 3);
    const int half = b & 1;
    const int head = (b >> 1) % NH;
    const int seq  = b / (2 * NH);

    const int tid  = threadIdx.x;
    const int lane = tid & 63;
    const int wave = tid >> 6;
    const int lr   = lane & 15;
    const int lg   = lane >> 4;

    const f16* qh = q  + (size_t)(seq*NH + head)*P*DH;
    const f16* kh = k  + (size_t)(seq*NH + head)*P*DH;
    const f16* vh = vt + (size_t)(seq*NH + head)*DH*P;

    {
        const int r0 = tid >> 3, ck = tid & 7;
        const int d0 = tid >> 5, cv = tid & 31;
        #pragma unroll
        for (int it = 0; it < 4; ++it) {
            const int row = it * 64 + r0;
            gload16(kh + row * 64 + ((ck ^ (row & 7)) * 8), kl + it * 8192 + tid * 16);
            const int d = it * 16 + d0;
            gload16(vh + d * 256 + (((cv & 24) | ((cv ^ d) & 7)) * 8), vl + it * 8192 + tid * 16);
        }
    }

    const int qr0 = half * 128 + wave * 16;
    const f16x8 aq0 = *(const f16x8*)(qh + (qr0 + lr) * DH + lg * 8);
    const f16x8 aq1 = *(const f16x8*)(qh + (qr0 + lr) * DH + 32 + lg * 8);

    __syncthreads();

    f32x4 s[16];
    #pragma unroll
    for (int t = 0; t < 16; ++t) s[t] = (f32x4){0.f,0.f,0.f,0.f};
    __builtin_amdgcn_s_setprio(1);
    #pragma unroll
    for (int t = 0; t < 16; ++t) {
        const int row = t * 16 + lr;
        const f16x8 b0 = *(const f16x8*)(kl + row * 128 + ((lg ^ (row & 7)) * 16));
        const f16x8 b1 = *(const f16x8*)(kl + row * 128 + (((lg + 4) ^ (row & 7)) * 16));
        s[t] = MFMA16(aq0, b0, s[t]);
        s[t] = MFMA16(aq1, b1, s[t]);
    }
    __builtin_amdgcn_s_setprio(0);

    float mx[4] = {-1e30f, -1e30f, -1e30f, -1e30f};
    #pragma unroll
    for (int t = 0; t < 16; ++t)
        #pragma unroll
        for (int i = 0; i < 4; ++i) mx[i] = fmaxf(mx[i], s[t][i]);
    #pragma unroll
    for (int st = 1; st < 16; st <<= 1)
        #pragma unroll
        for (int i = 0; i < 4; ++i) mx[i] = fmaxf(mx[i], __shfl_xor(mx[i], st));

    const float SCL = 0.125f * 1.44269504088896f;
    float rs[4] = {0.f, 0.f, 0.f, 0.f};
    #pragma unroll
    for (int t = 0; t < 16; ++t)
        #pragma unroll
        for (int i = 0; i < 4; ++i) {
            const float e = exp2f((s[t][i] - mx[i]) * SCL);
            s[t][i] = e;
            rs[i] += e;
        }
    #pragma unroll
    for (int st = 1; st < 16; st <<= 1)
        #pragma unroll
        for (int i = 0; i < 4; ++i) rs[i] += __shfl_xor(rs[i], st);

    char* pw = pl[wave];
    f32x4 o[4];
    #pragma unroll
    for (int t = 0; t < 4; ++t) o[t] = (f32x4){0.f,0.f,0.f,0.f};

    #pragma unroll
    for (int qq = 0; qq < 4; ++qq) {
        #pragma unroll
        for (int tt = 0; tt < 4; ++tt) {
            const int t = qq * 4 + tt;
            #pragma unroll
            for (int i = 0; i < 4; ++i) {
                const int r = lg * 4 + i;
                const int klocal = tt * 16 + lr;
                *(f16*)(pw + r * 128 + ((klocal * 2) ^ ((r & 7) << 4))) = (f16)s[t][i];
            }
        }
        __builtin_amdgcn_s_setprio(1);
        #pragma unroll
        for (int kol = 0; kol < 2; ++kol) {
            const f16x8 ap = *(const f16x8*)(pw + lr * 128 + (((kol * 4 + lg) ^ (lr & 7)) * 16));
            #pragma unroll
            for (int dt = 0; dt < 4; ++dt) {
                const int row = dt * 16 + lr;
                const int ch  = qq * 8 + kol * 4 + lg;
                const f16x8 bv_ = *(const f16x8*)(vl + row * 512 + (((ch & 24) | ((ch ^ row) & 7)) * 16));
                o[dt] = MFMA16(ap, bv_, o[dt]);
            }
        }
        __builtin_amdgcn_s_setprio(0);
    }

    #pragma unroll
    for (int i = 0; i < 4; ++i) rs[i] = 1.f / rs[i];
    float* op = out + ((size_t)seq * P + qr0) * DIMF + head * DH;
    #pragma unroll
    for (int t = 0; t < 4; ++t)
        #pragma unroll
        for (int i = 0; i < 4; ++i)
            op[(lg * 4 + i) * DIMF + t * 16 + lr] = o[t][i] * rs[i];
}

extern "C" void kernel_launch(void* const* d_in, const int* in_sizes, int n_in,
                              void* d_out, int out_size, void* d_ws, size_t ws_size,
                              hipStream_t stream) {
    const float* x  = (const float*)d_in[0];
    const float* Wq = (const float*)d_in[1];
    const float* bq = (const float*)d_in[2];
    const float* Wk = (const float*)d_in[3];
    const float* bk = (const float*)d_in[4];
    const float* Wv = (const float*)d_in[5];
    const float* bv = (const float*)d_in[6];
    float* out = (float*)d_out;

    f16* xh = (f16*)d_out;          // fp16 staging lives in d_out (fully consumed
    f16* wh = xh + XSZ;             // by proj_gemm before attn overwrites d_out)

    const size_t QSZ = (size_t)M * DIMF;
    f16* q  = (f16*)d_ws;
    f16* k  = q + QSZ;
    f16* vt = k + QSZ;

    const int convThreads = (int)((XSZ + 3 * WSZ) / 8);
    conv_kernel<<<convThreads / 256, 256, 0, stream>>>(x, Wq, Wk, Wv, xh, wh);
    proj_gemm<<<dim3(1536), 512, 0, stream>>>(xh, wh, bq, bk, bv, q, k, vt);
    attn_kernel<<<dim3(NSEQ * NH * 2), 512, 0, stream>>>(q, k, vt, out);
}